// Round 2
// baseline (115.450 us; speedup 1.0000x reference)
//
#include <hip/hip_runtime.h>
#include <hip/hip_bf16.h>
#include <stdint.h>

// Problem constants (from reference): B=32, NB=64, PL=20, FD=4096, H=1024
#define B_   32
#define NB_  64
#define PL_  20
#define FD_  4096
#define H_   1024
#define M_   (B_ * NB_)   // 2048 regions

typedef short bf16x8 __attribute__((ext_vector_type(8)));
typedef float f32x4  __attribute__((ext_vector_type(4)));

// f32 -> bf16 round-to-nearest-even
__device__ __forceinline__ ushort f2bf(float f) {
    uint32_t u = __builtin_bit_cast(uint32_t, f);
    u += 0x7fffu + ((u >> 16) & 1u);
    return (ushort)(u >> 16);
}

// ---------------------------------------------------------------------------
// Kernel 1: pooled[r][h] = (sum_p language[r][p][h]) / phrase_len[r], as bf16
// One thread per (r, 4 h's). 2048 blocks x 256 threads.
// ---------------------------------------------------------------------------
__global__ __launch_bounds__(256) void pool_kernel(
    const float* __restrict__ lang, const int* __restrict__ plen,
    ushort* __restrict__ pooled)
{
    int idx = blockIdx.x * 256 + threadIdx.x;
    int r = idx >> 8;            // region 0..2047 (block == region)
    int h = (idx & 255) << 2;    // 4 consecutive h per thread
    const float* base = lang + (size_t)r * (PL_ * H_) + h;
    float sx = 0.f, sy = 0.f, sz = 0.f, sw = 0.f;
#pragma unroll
    for (int p = 0; p < PL_; ++p) {
        float4 v = *(const float4*)(base + (size_t)p * H_);
        sx += v.x; sy += v.y; sz += v.z; sw += v.w;
    }
    float inv = 1.0f / (float)plen[r];
    ushort4 o = make_ushort4(f2bf(sx * inv), f2bf(sy * inv),
                             f2bf(sz * inv), f2bf(sw * inv));
    *(ushort4*)(pooled + (size_t)r * H_ + h) = o;
}

// ---------------------------------------------------------------------------
// Kernel 2: elementwise f32 -> bf16 (vectorized x4)
// ---------------------------------------------------------------------------
__global__ __launch_bounds__(256) void convert_kernel(
    const float* __restrict__ in, ushort* __restrict__ out, int n4)
{
    int i = blockIdx.x * 256 + threadIdx.x;
    if (i >= n4) return;
    float4 v = ((const float4*)in)[i];
    ushort4 o = make_ushort4(f2bf(v.x), f2bf(v.y), f2bf(v.z), f2bf(v.w));
    ((ushort4*)out)[i] = o;
}

// ---------------------------------------------------------------------------
// Kernel 3: Wt[n][k] = (bf16) W[k][n]  (transpose + convert, 32x32 LDS tiles)
// block = 256 threads (32x8), grid = (N/32, K/32)
// ---------------------------------------------------------------------------
__global__ __launch_bounds__(256) void transpose_convert(
    const float* __restrict__ W, ushort* __restrict__ Wt, int K, int N)
{
    __shared__ float tile[32][33];   // +1 pad: conflict-free both directions
    int n0 = blockIdx.x * 32, k0 = blockIdx.y * 32;
    int tx = threadIdx.x & 31, ty = threadIdx.x >> 5;   // ty in 0..7
#pragma unroll
    for (int i = 0; i < 32; i += 8)
        tile[ty + i][tx] = W[(size_t)(k0 + ty + i) * N + n0 + tx];
    __syncthreads();
#pragma unroll
    for (int i = 0; i < 32; i += 8)
        Wt[(size_t)(n0 + ty + i) * K + k0 + tx] = f2bf(tile[tx][ty + i]);
}

// ---------------------------------------------------------------------------
// Kernel 4: dual bf16 GEMM-BT:  C[M][N] = A[M][K] * Bt[N][K]^T + bias
// blockIdx.z selects problem (0: vision GEMM K=4096, 1: language GEMM K=1024)
// BM=128, BN=64, BK=32; 4 waves in 2x2; per-wave 64x32 out = acc[4][2] frags.
// Staging: global_load_lds width 16 (linear LDS layout required).
// ---------------------------------------------------------------------------
#define BM 128
#define BN 64
#define BK 32

__device__ __forceinline__ void async16(const void* g, void* l) {
    __builtin_amdgcn_global_load_lds(
        (const __attribute__((address_space(1))) void*)g,
        (__attribute__((address_space(3))) void*)l, 16, 0, 0);
}

__global__ __launch_bounds__(256) void gemm_bt_dual(
    const ushort* __restrict__ A1, const ushort* __restrict__ Bt1,
    const float* __restrict__ bias1, float* __restrict__ C1, int K1,
    const ushort* __restrict__ A2, const ushort* __restrict__ Bt2,
    const float* __restrict__ bias2, float* __restrict__ C2, int K2)
{
    __shared__ ushort As[BM * BK];   // 8 KB, row-major [128][32]
    __shared__ ushort Bs[BN * BK];   // 4 KB, row-major [64][32]

    const ushort* A; const ushort* Bt; const float* bias; float* C; int K;
    if (blockIdx.z == 0) { A = A1; Bt = Bt1; bias = bias1; C = C1; K = K1; }
    else                 { A = A2; Bt = Bt2; bias = bias2; C = C2; K = K2; }

    const int N = H_;
    int tid  = threadIdx.x;
    int wave = tid >> 6, lane = tid & 63;
    int lx = lane & 15, lz = lane >> 4;
    int wr = wave >> 1, wc = wave & 1;
    int row0 = blockIdx.x * BM;
    int col0 = blockIdx.y * BN;

    size_t Kb = (size_t)K * 2;       // bytes per logical row

    // Staging decomposition: thread t covers bytes t*16 of each 4096B chunk.
    int off  = tid * 16;
    int a_r  = off >> 6;             // row within tile (64 B per row)
    int a_cb = off & 63;             // byte within row

    const char* Ag = (const char*)A  + (size_t)row0 * Kb;
    const char* Bg = (const char*)Bt + (size_t)col0 * Kb;

    // Wave-uniform LDS bases (dest = base + lane*16, HW rule)
    char* AsW0 = (char*)As + wave * 1024;          // rows 0..63
    char* AsW1 = (char*)As + 4096 + wave * 1024;   // rows 64..127
    char* BsW  = (char*)Bs + wave * 1024;          // rows 0..63

    f32x4 acc[4][2] = {};

    int nk = K >> 5;
    for (int kt = 0; kt < nk; ++kt) {
        size_t ko = (size_t)kt * 64;
        async16(Ag + (size_t)a_r * Kb + ko + a_cb, AsW0);
        async16(Ag + (size_t)(a_r + 64) * Kb + ko + a_cb, AsW1);
        async16(Bg + (size_t)a_r * Kb + ko + a_cb, BsW);
        asm volatile("s_waitcnt vmcnt(0)" ::: "memory");
        __syncthreads();

        bf16x8 af[4], bfr[2];
#pragma unroll
        for (int m = 0; m < 4; ++m)
            af[m] = *(const bf16x8*)&As[(wr * 64 + m * 16 + lx) * BK + lz * 8];
#pragma unroll
        for (int n = 0; n < 2; ++n)
            bfr[n] = *(const bf16x8*)&Bs[(wc * 32 + n * 16 + lx) * BK + lz * 8];
#pragma unroll
        for (int m = 0; m < 4; ++m)
#pragma unroll
            for (int n = 0; n < 2; ++n)
                acc[m][n] = __builtin_amdgcn_mfma_f32_16x16x32_bf16(
                    af[m], bfr[n], acc[m][n], 0, 0, 0);
        __syncthreads();
    }

    // Epilogue. D frag: col = lane&15, row = (lane>>4)*4 + reg  [verified map]
#pragma unroll
    for (int m = 0; m < 4; ++m) {
        int row = row0 + wr * 64 + m * 16 + lz * 4;
#pragma unroll
        for (int n = 0; n < 2; ++n) {
            int col = col0 + wc * 32 + n * 16 + lx;
            float bb = bias[col];
#pragma unroll
            for (int r = 0; r < 4; ++r)
                C[(size_t)(row + r) * N + col] = acc[m][n][r] + bb;
        }
    }
}

// ---------------------------------------------------------------------------
extern "C" void kernel_launch(void* const* d_in, const int* in_sizes, int n_in,
                              void* d_out, int out_size, void* d_ws, size_t ws_size,
                              hipStream_t stream) {
    const float* vision   = (const float*)d_in[0];   // [2048, 4096]
    const float* language = (const float*)d_in[1];   // [2048, 20, 1024]
    const int*   plen     = (const int*)d_in[2];     // [2048]
    const float* Wv       = (const float*)d_in[3];   // [4096, 1024]
    const float* bv       = (const float*)d_in[4];   // [1024]
    const float* Wl       = (const float*)d_in[5];   // [1024, 1024]
    const float* bl       = (const float*)d_in[6];   // [1024]

    float* out      = (float*)d_out;
    float* lang_map = out;                        // output 0: [2048,1024]
    float* vis_map  = out + (size_t)M_ * H_;      // output 1: [2048,1024]

    char* ws = (char*)d_ws;
    ushort* pooled  = (ushort*)(ws);                   // 4 MB  [2048][1024]
    ushort* visionb = (ushort*)(ws + (4u  << 20));     // 16 MB [2048][4096]
    ushort* WvT     = (ushort*)(ws + (20u << 20));     // 8 MB  [1024][4096]
    ushort* WlT     = (ushort*)(ws + (28u << 20));     // 2 MB  [1024][1024]

    hipLaunchKernelGGL(pool_kernel, dim3(M_), dim3(256), 0, stream,
                       language, plen, pooled);
    hipLaunchKernelGGL(convert_kernel, dim3((M_ * FD_ / 4) / 256), dim3(256), 0, stream,
                       vision, visionb, M_ * FD_ / 4);
    hipLaunchKernelGGL(transpose_convert, dim3(H_ / 32, FD_ / 32), dim3(256), 0, stream,
                       Wv, WvT, FD_, H_);
    hipLaunchKernelGGL(transpose_convert, dim3(H_ / 32, H_ / 32), dim3(256), 0, stream,
                       Wl, WlT, H_, H_);
    hipLaunchKernelGGL(gemm_bt_dual, dim3(M_ / BM, H_ / BN, 2), dim3(256), 0, stream,
                       visionb, WvT, bv, vis_map, FD_,
                       pooled,  WlT, bl, lang_map, H_);
}

// Round 4
// 104.995 us; speedup vs baseline: 1.0996x; 1.0996x over previous
//
#include <hip/hip_runtime.h>
#include <hip/hip_bf16.h>
#include <stdint.h>

// Problem constants (from reference): B=32, NB=64, PL=20, FD=4096, H=1024
#define B_   32
#define NB_  64
#define PL_  20
#define FD_  4096
#define H_   1024
#define M_   (B_ * NB_)   // 2048 regions

typedef short bf16x8 __attribute__((ext_vector_type(8)));
typedef float f32x4  __attribute__((ext_vector_type(4)));

// f32 -> bf16 round-to-nearest-even
__device__ __forceinline__ ushort f2bf(float f) {
    uint32_t u = __builtin_bit_cast(uint32_t, f);
    u += 0x7fffu + ((u >> 16) & 1u);
    return (ushort)(u >> 16);
}

// ---------------------------------------------------------------------------
// Fused prep kernel (block-range dispatch, saves ~3 launch gaps):
//   blocks [0, 2048)          : pool language -> pooled bf16 (1 region/block)
//   blocks [2048, 10240)      : vision f32 -> bf16 (1024 elems/block)
//   blocks [10240, 14336)     : WvT[n][k] = bf16(Wv[k][n])  (32x32 tiles)
//   blocks [14336, 15360)     : WlT[n][k] = bf16(Wl[k][n])
// ---------------------------------------------------------------------------
__global__ __launch_bounds__(256) void prep_kernel(
    const float* __restrict__ lang, const int* __restrict__ plen,
    ushort* __restrict__ pooled,
    const float* __restrict__ vision, ushort* __restrict__ visionb,
    const float* __restrict__ Wv, ushort* __restrict__ WvT,
    const float* __restrict__ Wl, ushort* __restrict__ WlT)
{
    __shared__ float tile[32][33];   // transpose staging (+1 pad)
    int blk = blockIdx.x;
    int tid = threadIdx.x;

    if (blk < M_) {
        // ---- pool: region r = blk, thread covers 4 h's ----
        int r = blk;
        int h = tid << 2;
        const float* base = lang + (size_t)r * (PL_ * H_) + h;
        float sx = 0.f, sy = 0.f, sz = 0.f, sw = 0.f;
#pragma unroll
        for (int p = 0; p < PL_; ++p) {
            float4 v = *(const float4*)(base + (size_t)p * H_);
            sx += v.x; sy += v.y; sz += v.z; sw += v.w;
        }
        float inv = 1.0f / (float)plen[r];
        ushort4 o = make_ushort4(f2bf(sx * inv), f2bf(sy * inv),
                                 f2bf(sz * inv), f2bf(sw * inv));
        *(ushort4*)(pooled + (size_t)r * H_ + h) = o;
    } else if (blk < M_ + 8192) {
        // ---- vision f32 -> bf16, x4 vectorized ----
        int i = (blk - M_) * 256 + tid;        // i < 2048*4096/4
        float4 v = ((const float4*)vision)[i];
        ushort4 o = make_ushort4(f2bf(v.x), f2bf(v.y), f2bf(v.z), f2bf(v.w));
        ((ushort4*)visionb)[i] = o;
    } else {
        const float* W; ushort* Wt; int K, b;
        if (blk < M_ + 8192 + 4096) { W = Wv; Wt = WvT; K = FD_; b = blk - (M_ + 8192); }
        else                        { W = Wl; Wt = WlT; K = H_;  b = blk - (M_ + 8192 + 4096); }
        int n0 = (b & 31) * 32, k0 = (b >> 5) * 32;
        int tx = tid & 31, ty = tid >> 5;      // ty in 0..7
#pragma unroll
        for (int i = 0; i < 32; i += 8)
            tile[ty + i][tx] = W[(size_t)(k0 + ty + i) * H_ + n0 + tx];
        __syncthreads();
#pragma unroll
        for (int i = 0; i < 32; i += 8)
            Wt[(size_t)(n0 + ty + i) * K + k0 + tx] = f2bf(tile[tx][ty + i]);
    }
}

// ---------------------------------------------------------------------------
// Dual bf16 GEMM-BT with 2-phase prefetch:  C[M][N] = A[M][K] * Bt[N][K]^T + b
// blockIdx.z: 0 = vision GEMM (K=4096), 1 = language GEMM (K=1024)
// BM=128, BN=64, BK=64; 4 waves (2x2); per-wave 64x32 out; 16 MFMA/K-step.
// Double-buffered LDS (48 KB), STAGE(t+1) issued before compute(t),
// one __syncthreads per K-step (implicit vmcnt(0) drain => race-free).
// ---------------------------------------------------------------------------
#define BM 128
#define BN 64
#define BK 64

__device__ __forceinline__ void async16(const void* g, void* l) {
    __builtin_amdgcn_global_load_lds(
        (const __attribute__((address_space(1))) void*)g,
        (__attribute__((address_space(3))) void*)l, 16, 0, 0);
}

// Stage one 128x64 A-tile (16 KB) + 64x64 B-tile (8 KB), bf16, linear LDS.
// Per issue j: byte off = j*4096 + wave*1024 + lane*16; row = off>>7 (128 B/row).
__device__ __forceinline__ void stage_tile(
    const char* Ag, const char* Bg, size_t Kb, size_t ko,
    char* AsB, char* BsB, int wave, int lane)
{
#pragma unroll
    for (int j = 0; j < 4; ++j) {
        int off = j * 4096 + wave * 1024 + lane * 16;
        async16(Ag + (size_t)(off >> 7) * Kb + ko + (off & 127),
                AsB + j * 4096 + wave * 1024);
    }
#pragma unroll
    for (int j = 0; j < 2; ++j) {
        int off = j * 4096 + wave * 1024 + lane * 16;
        async16(Bg + (size_t)(off >> 7) * Kb + ko + (off & 127),
                BsB + j * 4096 + wave * 1024);
    }
}

__global__ __launch_bounds__(256) void gemm_bt_dual(
    const ushort* __restrict__ A1, const ushort* __restrict__ Bt1,
    const float* __restrict__ bias1, float* __restrict__ C1, int K1,
    const ushort* __restrict__ A2, const ushort* __restrict__ Bt2,
    const float* __restrict__ bias2, float* __restrict__ C2, int K2)
{
    __shared__ ushort As[2][BM * BK];   // 2 x 16 KB
    __shared__ ushort Bs[2][BN * BK];   // 2 x  8 KB

    const ushort* A; const ushort* Bt; const float* bias; float* C; int K;
    if (blockIdx.z == 0) { A = A1; Bt = Bt1; bias = bias1; C = C1; K = K1; }
    else                 { A = A2; Bt = Bt2; bias = bias2; C = C2; K = K2; }

    const int N = H_;
    int tid  = threadIdx.x;
    int wave = tid >> 6, lane = tid & 63;
    int lx = lane & 15, lz = lane >> 4;
    int wr = wave >> 1, wc = wave & 1;
    int row0 = blockIdx.x * BM;
    int col0 = blockIdx.y * BN;

    size_t Kb = (size_t)K * 2;          // bytes per logical row

    const char* Ag = (const char*)A  + (size_t)row0 * Kb;
    const char* Bg = (const char*)Bt + (size_t)col0 * Kb;

    f32x4 acc[4][2] = {};

    int nk = K >> 6;                    // K-steps of 64
    // prologue: stage tile 0
    stage_tile(Ag, Bg, Kb, 0, (char*)As[0], (char*)Bs[0], wave, lane);
    __syncthreads();                    // drains vmcnt(0)

    int cur = 0;
    for (int kt = 0; kt < nk; ++kt) {
        // issue next tile's loads BEFORE compute (overlap HBM latency)
        if (kt + 1 < nk)
            stage_tile(Ag, Bg, Kb, (size_t)(kt + 1) * 128,
                       (char*)As[cur ^ 1], (char*)Bs[cur ^ 1], wave, lane);

        bf16x8 af[2][4], bfr[2][2];
#pragma unroll
        for (int kk = 0; kk < 2; ++kk) {
#pragma unroll
            for (int m = 0; m < 4; ++m)
                af[kk][m] = *(const bf16x8*)
                    &As[cur][(wr * 64 + m * 16 + lx) * BK + kk * 32 + lz * 8];
#pragma unroll
            for (int n = 0; n < 2; ++n)
                bfr[kk][n] = *(const bf16x8*)
                    &Bs[cur][(wc * 32 + n * 16 + lx) * BK + kk * 32 + lz * 8];
        }
#pragma unroll
        for (int kk = 0; kk < 2; ++kk)
#pragma unroll
            for (int m = 0; m < 4; ++m)
#pragma unroll
                for (int n = 0; n < 2; ++n)
                    acc[m][n] = __builtin_amdgcn_mfma_f32_16x16x32_bf16(
                        af[kk][m], bfr[kk][n], acc[m][n], 0, 0, 0);

        __syncthreads();                // drain: next tile staged, buf reusable
        cur ^= 1;
    }

    // Epilogue. D frag: col = lane&15, row = (lane>>4)*4 + reg  [verified map]
#pragma unroll
    for (int m = 0; m < 4; ++m) {
        int row = row0 + wr * 64 + m * 16 + lz * 4;
#pragma unroll
        for (int n = 0; n < 2; ++n) {
            int col = col0 + wc * 32 + n * 16 + lx;
            float bb = bias[col];
#pragma unroll
            for (int r = 0; r < 4; ++r)
                C[(size_t)(row + r) * N + col] = acc[m][n][r] + bb;
        }
    }
}

// ---------------------------------------------------------------------------
extern "C" void kernel_launch(void* const* d_in, const int* in_sizes, int n_in,
                              void* d_out, int out_size, void* d_ws, size_t ws_size,
                              hipStream_t stream) {
    const float* vision   = (const float*)d_in[0];   // [2048, 4096]
    const float* language = (const float*)d_in[1];   // [2048, 20, 1024]
    const int*   plen     = (const int*)d_in[2];     // [2048]
    const float* Wv       = (const float*)d_in[3];   // [4096, 1024]
    const float* bv       = (const float*)d_in[4];   // [1024]
    const float* Wl       = (const float*)d_in[5];   // [1024, 1024]
    const float* bl       = (const float*)d_in[6];   // [1024]

    float* out      = (float*)d_out;
    float* lang_map = out;                        // output 0: [2048,1024]
    float* vis_map  = out + (size_t)M_ * H_;      // output 1: [2048,1024]

    char* ws = (char*)d_ws;
    ushort* pooled  = (ushort*)(ws);                   // 4 MB  [2048][1024]
    ushort* visionb = (ushort*)(ws + (4u  << 20));     // 16 MB [2048][4096]
    ushort* WvT     = (ushort*)(ws + (20u << 20));     // 8 MB  [1024][4096]
    ushort* WlT     = (ushort*)(ws + (28u << 20));     // 2 MB  [1024][1024]

    // prep: 2048 pool + 8192 convert + 4096 WvT + 1024 WlT = 15360 blocks
    hipLaunchKernelGGL(prep_kernel, dim3(15360), dim3(256), 0, stream,
                       language, plen, pooled, vision, visionb,
                       Wv, WvT, Wl, WlT);
    hipLaunchKernelGGL(gemm_bt_dual, dim3(M_ / BM, H_ / BN, 2), dim3(256), 0, stream,
                       visionb, WvT, bv, vis_map, FD_,
                       pooled,  WlT, bl, lang_map, H_);
}